// Round 6
// baseline (620.087 us; speedup 1.0000x reference)
//
#include <hip/hip_runtime.h>
#include <hip/hip_cooperative_groups.h>
#include <math.h>

namespace cg = cooperative_groups;

#define N_NODES 262144
#define N_EDGES 2097152
#define NB 512                  // dst buckets (dst >> 9), 512 nodes each
#define BN 512                  // nodes per bucket
#define NA 512                  // hist/place slice blocks
#define EPB (N_EDGES / NA)      // 4096 edges per slice
#define HID 200
#define G_TAB 256
#define GRID (NA + G_TAB)       // 768 blocks = 3 per CU
#define RLO (-8.0f)
#define RHI (8.0f)

__global__ __launch_bounds__(256, 3)
void k_all(const float* __restrict__ x,
           const int* __restrict__ src, const int* __restrict__ dst,
           const float* __restrict__ W0, const float* __restrict__ B0,
           const float* __restrict__ W1, const float* __restrict__ B1,
           const float* __restrict__ W2, const float* __restrict__ B2,
           const float* __restrict__ W3, const float* __restrict__ B3,
           const float* __restrict__ W4, const float* __restrict__ B4,
           const float* __restrict__ W5, const float* __restrict__ B5,
           const float* __restrict__ W6, const float* __restrict__ B6,
           const float* __restrict__ W7, const float* __restrict__ B7,
           float* __restrict__ out,
           unsigned* __restrict__ elist, unsigned* __restrict__ bh,
           unsigned* __restrict__ offs, unsigned* __restrict__ totals,
           unsigned* __restrict__ basearr, float* __restrict__ yg,
           float* __restrict__ T)
{
    cg::grid_group grid = cg::this_grid();
    __shared__ unsigned sm[520];     // union: hist/cur/cnt/accf (512) | hs(2x256)+ps(4)
    const int t = threadIdx.x;
    const int b = blockIdx.x;

    // ======== Phase A: histogram (b < NA)  ||  MLP table (b >= NA) ========
    if (b < NA) {
        sm[t] = 0u; sm[t + 256] = 0u;
        __syncthreads();
        const int4* d4 = (const int4*)dst;
        int base0 = b * (EPB / 4);
        #pragma unroll
        for (int i = 0; i < EPB / (4 * 256); i++) {      // 4 iters
            int4 d = d4[base0 + i * 256 + t];
            atomicAdd(&sm[d.x >> 9], 1u);
            atomicAdd(&sm[d.y >> 9], 1u);
            atomicAdd(&sm[d.z >> 9], 1u);
            atomicAdd(&sm[d.w >> 9], 1u);
        }
        __syncthreads();
        bh[t * NA + b] = sm[t];
        bh[(t + 256) * NA + b] = sm[t + 256];
    } else {
        // -------- table: one grid point per block, fixed range --------
        float* hs = (float*)sm;            // [2][256] (stride 256, 16B-aligned)
        float step = (RHI - RLO) / (float)(G_TAB - 1);
        float gp = RLO + (float)(b - NA) * step;
        if (t < HID) hs[t] = fmaxf(fmaf(gp, W0[t], B0[t]), 0.f);
        __syncthreads();
        const float* Ws[6] = {W1, W2, W3, W4, W5, W6};
        const float* Bs[6] = {B1, B2, B3, B4, B5, B6};
        int cur = 0;
        for (int l = 0; l < 6; l++) {
            float acc = 0.f;
            if (t < HID) {
                const float* W = Ws[l] + t;
                acc = Bs[l][t];
                #pragma unroll 5
                for (int k4 = 0; k4 < HID / 4; k4++) {
                    float4 hv = *(const float4*)&hs[cur * 256 + k4 * 4];
                    const float* Wp = W + (k4 * 4) * HID;
                    acc = fmaf(hv.x, Wp[0],       acc);
                    acc = fmaf(hv.y, Wp[HID],     acc);
                    acc = fmaf(hv.z, Wp[2 * HID], acc);
                    acc = fmaf(hv.w, Wp[3 * HID], acc);
                }
            }
            __syncthreads();
            if (t < HID) hs[(1 - cur) * 256 + t] = fmaxf(acc, 0.f);
            __syncthreads();
            cur = 1 - cur;
        }
        float part = (t < HID) ? hs[cur * 256 + t] * W7[t] : 0.f;
        #pragma unroll
        for (int o = 32; o > 0; o >>= 1) part += __shfl_down(part, o);
        float* ps = (float*)&sm[512];
        if ((t & 63) == 0) ps[t >> 6] = part;
        __syncthreads();
        if (t == 0) T[b - NA] = ps[0] + ps[1] + ps[2] + ps[3] + B7[0];
    }
    grid.sync();

    // ======== S1: one wave per bucket — scan over the NA slices ========
    if (b < NB / 4) {                       // 128 blocks, 4 waves each
        int lane = t & 63;
        int bk = b * 4 + (t >> 6);
        const uint4* row = (const uint4*)&bh[bk * NA];   // 128 uint4
        uint4 v[2];
        unsigned s = 0;
        #pragma unroll
        for (int i = 0; i < 2; i++) {
            v[i] = row[lane * 2 + i];
            s += v[i].x + v[i].y + v[i].z + v[i].w;
        }
        unsigned inc = s;
        #pragma unroll
        for (int o = 1; o < 64; o <<= 1) {
            unsigned u = __shfl_up(inc, o);
            if (lane >= o) inc += u;
        }
        unsigned run = inc - s;             // exclusive
        unsigned* orow = &offs[bk * NA + lane * 8];
        #pragma unroll
        for (int i = 0; i < 2; i++) {
            orow[4 * i + 0] = run; run += v[i].x;
            orow[4 * i + 1] = run; run += v[i].y;
            orow[4 * i + 2] = run; run += v[i].z;
            orow[4 * i + 3] = run; run += v[i].w;
        }
        if (lane == 63) totals[bk] = inc;
    }
    grid.sync();

    // ======== S2: block 0 exclusive-scans 512 bucket totals ========
    if (b == 0) {
        unsigned v0 = totals[2 * t], v1 = totals[2 * t + 1];
        unsigned s2 = v0 + v1;
        sm[t] = s2;
        __syncthreads();
        for (int o = 1; o < 256; o <<= 1) {
            unsigned u = (t >= o) ? sm[t - o] : 0u;
            __syncthreads();
            sm[t] += u;
            __syncthreads();
        }
        unsigned excl = sm[t] - s2;
        basearr[2 * t]     = excl;
        basearr[2 * t + 1] = excl + v0;
    }
    grid.sync();

    // ======== P: place packed edges (src<<9 | dst&511) ========
    if (b < NA) {
        sm[t]       = basearr[t]       + offs[t * NA + b];
        sm[t + 256] = basearr[t + 256] + offs[(t + 256) * NA + b];
        __syncthreads();
        const int4* s4 = (const int4*)src;
        const int4* d4 = (const int4*)dst;
        int base0 = b * (EPB / 4);
        #pragma unroll
        for (int i = 0; i < EPB / (4 * 256); i++) {
            int4 sv = s4[base0 + i * 256 + t];
            int4 dv = d4[base0 + i * 256 + t];
            unsigned p;
            p = atomicAdd(&sm[dv.x >> 9], 1u);
            elist[p] = ((unsigned)sv.x << 9) | (unsigned)(dv.x & 511);
            p = atomicAdd(&sm[dv.y >> 9], 1u);
            elist[p] = ((unsigned)sv.y << 9) | (unsigned)(dv.y & 511);
            p = atomicAdd(&sm[dv.z >> 9], 1u);
            elist[p] = ((unsigned)sv.z << 9) | (unsigned)(dv.z & 511);
            p = atomicAdd(&sm[dv.w >> 9], 1u);
            elist[p] = ((unsigned)sv.w << 9) | (unsigned)(dv.w & 511);
        }
    }
    grid.sync();

    // ======== B1: per-bucket degree -> inv_sqrt, y = x*inv ========
    float iv0 = 0.f, iv1 = 0.f, ys0 = 0.f, ys1 = 0.f;
    unsigned lo = 0, hi = 0;
    if (b < NB) {
        sm[t] = 0u; sm[t + 256] = 0u;
        __syncthreads();
        lo = basearr[b];
        hi = (b == NB - 1) ? N_EDGES : basearr[b + 1];
        for (unsigned j = lo + t; j < hi; j += 256)
            atomicAdd(&sm[elist[j] & 511u], 1u);
        __syncthreads();
        int i0 = b * BN;
        iv0 = rsqrtf((float)(sm[t] + 1u));          // +1 self-loop
        iv1 = rsqrtf((float)(sm[t + 256] + 1u));
        ys0 = x[i0 + t] * iv0;
        ys1 = x[i0 + t + 256] * iv1;
        yg[i0 + t] = ys0;
        yg[i0 + t + 256] = ys1;
    }
    grid.sync();

    // ======== B2: LDS accumulate y[src]; fused interp + sigmoid ========
    if (b < NB) {
        float* accf = (float*)sm;
        accf[t] = 0.f; accf[t + 256] = 0.f;
        __syncthreads();
        for (unsigned j = lo + t; j < hi; j += 256) {
            unsigned p = elist[j];
            atomicAdd(&accf[p & 511u], yg[p >> 9]);
        }
        __syncthreads();
        float inv_step = (float)(G_TAB - 1) / (RHI - RLO);
        int i0 = b * BN;
        {
            float g = iv0 * (accf[t] + ys0);
            float u = (g - RLO) * inv_step;
            int j = min(max((int)u, 0), G_TAB - 2);
            float fr = u - (float)j;
            float logit = fmaf(fr, T[j + 1] - T[j], T[j]);
            out[i0 + t] = 1.f / (1.f + expf(-logit));
        }
        {
            float g = iv1 * (accf[t + 256] + ys1);
            float u = (g - RLO) * inv_step;
            int j = min(max((int)u, 0), G_TAB - 2);
            float fr = u - (float)j;
            float logit = fmaf(fr, T[j + 1] - T[j], T[j]);
            out[i0 + t + 256] = 1.f / (1.f + expf(-logit));
        }
    }
}

extern "C" void kernel_launch(void* const* d_in, const int* in_sizes, int n_in,
                              void* d_out, int out_size, void* d_ws, size_t ws_size,
                              hipStream_t stream) {
    const float* x = (const float*)d_in[0];
    const int* e = (const int*)d_in[1];          // int32 edge_index [2][E]
    const int* src = e;
    const int* dst = e + N_EDGES;
    const float* W0 = (const float*)d_in[2];  const float* B0 = (const float*)d_in[3];
    const float* W1 = (const float*)d_in[4];  const float* B1 = (const float*)d_in[5];
    const float* W2 = (const float*)d_in[6];  const float* B2 = (const float*)d_in[7];
    const float* W3 = (const float*)d_in[8];  const float* B3 = (const float*)d_in[9];
    const float* W4 = (const float*)d_in[10]; const float* B4 = (const float*)d_in[11];
    const float* W5 = (const float*)d_in[12]; const float* B5 = (const float*)d_in[13];
    const float* W6 = (const float*)d_in[14]; const float* B6 = (const float*)d_in[15];
    const float* W7 = (const float*)d_in[16]; const float* B7 = (const float*)d_in[17];
    float* out = (float*)d_out;

    // ws layout (4B words):
    // elist(E) | bh(NB*NA) | offs(NB*NA) | totals(NB) | basearr(NB) | yg(N) | T(G_TAB)
    unsigned* wsu = (unsigned*)d_ws;
    unsigned* elist   = wsu;
    unsigned* bh      = elist + N_EDGES;
    unsigned* offs    = bh + NB * NA;
    unsigned* totals  = offs + NB * NA;
    unsigned* basearr = totals + NB;
    float* yg = (float*)(basearr + NB);
    float* T  = yg + N_NODES;

    void* args[] = {
        (void*)&x, (void*)&src, (void*)&dst,
        (void*)&W0, (void*)&B0, (void*)&W1, (void*)&B1,
        (void*)&W2, (void*)&B2, (void*)&W3, (void*)&B3,
        (void*)&W4, (void*)&B4, (void*)&W5, (void*)&B5,
        (void*)&W6, (void*)&B6, (void*)&W7, (void*)&B7,
        (void*)&out,
        (void*)&elist, (void*)&bh, (void*)&offs, (void*)&totals,
        (void*)&basearr, (void*)&yg, (void*)&T
    };
    hipLaunchCooperativeKernel((const void*)k_all, dim3(GRID), dim3(256),
                               args, 0, stream);
}

// Round 7
// 246.837 us; speedup vs baseline: 2.5121x; 2.5121x over previous
//
#include <hip/hip_runtime.h>
#include <math.h>

#define N_NODES 262144
#define N_EDGES 2097152
#define NB 512                  // dst buckets (dst >> 9), 512 nodes each
#define BN 512                  // nodes per bucket
#define NAH 256                 // hist/place slice blocks
#define EPB (N_EDGES / NAH)     // 8192 edges per slice
#define HID 200
#define G_TAB 256
#define PT 4                    // grid points per table block
#define TB (G_TAB / PT)         // 64 table blocks
#define RLO (-8.0f)
#define RHI (8.0f)

// ==== K1: histogram (blocks 0..NAH-1)  ||  MLP table (blocks NAH..NAH+TB-1) ====
// Independent halves, no sync needed — table overlaps hist for free.
__global__ void k1_hist_table(const int4* __restrict__ dst4, unsigned* __restrict__ bh,
                              const float* __restrict__ W0, const float* __restrict__ B0,
                              const float* __restrict__ W1, const float* __restrict__ B1,
                              const float* __restrict__ W2, const float* __restrict__ B2,
                              const float* __restrict__ W3, const float* __restrict__ B3,
                              const float* __restrict__ W4, const float* __restrict__ B4,
                              const float* __restrict__ W5, const float* __restrict__ B5,
                              const float* __restrict__ W6, const float* __restrict__ B6,
                              const float* __restrict__ W7, const float* __restrict__ B7,
                              float* __restrict__ T) {
    __shared__ float smf[2 * PT * 256 + 16];     // 8.3 KB: hist uses first 2KB as uint
    unsigned* smu = (unsigned*)smf;
    const int t = threadIdx.x, b = blockIdx.x;

    if (b < NAH) {
        smu[t] = 0u; smu[t + 256] = 0u;
        __syncthreads();
        int base0 = b * (EPB / 4);
        #pragma unroll
        for (int i = 0; i < EPB / 1024; i++) {   // 8 iters, int4 loads
            int4 d = dst4[base0 + i * 256 + t];
            atomicAdd(&smu[d.x >> 9], 1u);
            atomicAdd(&smu[d.y >> 9], 1u);
            atomicAdd(&smu[d.z >> 9], 1u);
            atomicAdd(&smu[d.w >> 9], 1u);
        }
        __syncthreads();
        bh[t * NAH + b] = smu[t];                // bucket-major for K2 coalesced reads
        bh[(t + 256) * NAH + b] = smu[t + 256];
    } else {
        // ---- table: PT grid points per block, thread = neuron ----
        int pt0 = (b - NAH) * PT;
        float step = (RHI - RLO) / (float)(G_TAB - 1);
        float* hs = smf;                          // [2][PT][256]
        if (t < HID) {
            float w = W0[t], bb = B0[t];
            #pragma unroll
            for (int p = 0; p < PT; p++) {
                float gp = RLO + (float)(pt0 + p) * step;
                hs[p * 256 + t] = fmaxf(fmaf(gp, w, bb), 0.f);
            }
        }
        __syncthreads();
        const float* Ws[6] = {W1, W2, W3, W4, W5, W6};
        const float* Bs[6] = {B1, B2, B3, B4, B5, B6};
        int cur = 0;
        for (int l = 0; l < 6; l++) {
            float acc[PT];
            if (t < HID) {
                const float* W = Ws[l] + t;
                float bb = Bs[l][t];
                #pragma unroll
                for (int p = 0; p < PT; p++) acc[p] = bb;
                #pragma unroll 5
                for (int k4 = 0; k4 < HID / 4; k4++) {
                    const float* Wp = W + (k4 * 4) * HID;
                    float w0 = Wp[0], w1 = Wp[HID], w2 = Wp[2 * HID], w3 = Wp[3 * HID];
                    #pragma unroll
                    for (int p = 0; p < PT; p++) {
                        float4 hv = *(const float4*)&hs[cur * PT * 256 + p * 256 + k4 * 4];
                        acc[p] = fmaf(hv.x, w0, acc[p]);
                        acc[p] = fmaf(hv.y, w1, acc[p]);
                        acc[p] = fmaf(hv.z, w2, acc[p]);
                        acc[p] = fmaf(hv.w, w3, acc[p]);
                    }
                }
            }
            __syncthreads();
            if (t < HID) {
                #pragma unroll
                for (int p = 0; p < PT; p++)
                    hs[(1 - cur) * PT * 256 + p * 256 + t] = fmaxf(acc[p], 0.f);
            }
            __syncthreads();
            cur = 1 - cur;
        }
        // layer 7: PT block-wide dot products
        float w7 = (t < HID) ? W7[t] : 0.f;
        float part[PT];
        #pragma unroll
        for (int p = 0; p < PT; p++) {
            part[p] = (t < HID) ? hs[cur * PT * 256 + p * 256 + t] * w7 : 0.f;
            #pragma unroll
            for (int o = 32; o > 0; o >>= 1) part[p] += __shfl_down(part[p], o);
        }
        float* ps = smf + 2 * PT * 256;           // [4 waves][PT]
        if ((t & 63) == 0) {
            #pragma unroll
            for (int p = 0; p < PT; p++) ps[(t >> 6) * PT + p] = part[p];
        }
        __syncthreads();
        if (t == 0) {
            #pragma unroll
            for (int p = 0; p < PT; p++)
                T[pt0 + p] = ps[p] + ps[PT + p] + ps[2 * PT + p] + ps[3 * PT + p] + B7[0];
        }
    }
}

// ==== K2: one wave per bucket — exclusive scan over the NAH slices ====
__global__ void k2_s1(const unsigned* __restrict__ bh, unsigned* __restrict__ offs,
                      unsigned* __restrict__ totals) {
    int lane = threadIdx.x & 63;
    int bk = blockIdx.x * 4 + (threadIdx.x >> 6);    // 4 waves/block
    const uint4* row = (const uint4*)&bh[bk * NAH];  // 64 uint4 = 256 slices
    uint4 v = row[lane];
    unsigned s = v.x + v.y + v.z + v.w;
    unsigned inc = s;
    #pragma unroll
    for (int o = 1; o < 64; o <<= 1) {
        unsigned u = __shfl_up(inc, o);
        if (lane >= o) inc += u;
    }
    unsigned run = inc - s;                          // exclusive
    unsigned* orow = &offs[bk * NAH + lane * 4];
    orow[0] = run; run += v.x;
    orow[1] = run; run += v.y;
    orow[2] = run; run += v.z;
    orow[3] = run;
    if (lane == 63) totals[bk] = inc;
}

// ==== K3: in-block scan of bucket totals + place packed edges ====
__global__ void k3_place(const int4* __restrict__ src4, const int4* __restrict__ dst4,
                         const unsigned* __restrict__ offs, const unsigned* __restrict__ totals,
                         unsigned* __restrict__ basearr, unsigned* __restrict__ elist) {
    __shared__ unsigned cur[NB];
    __shared__ unsigned s[256];
    int t = threadIdx.x, b = blockIdx.x;
    unsigned v0 = totals[2 * t], v1 = totals[2 * t + 1];
    s[t] = v0 + v1;
    __syncthreads();
    for (int o = 1; o < 256; o <<= 1) {
        unsigned u = (t >= o) ? s[t - o] : 0u;
        __syncthreads();
        s[t] += u;
        __syncthreads();
    }
    unsigned excl = s[t] - (v0 + v1);
    cur[2 * t]     = excl      + offs[(2 * t) * NAH + b];
    cur[2 * t + 1] = excl + v0 + offs[(2 * t + 1) * NAH + b];
    if (b == 0) {
        basearr[2 * t] = excl;
        basearr[2 * t + 1] = excl + v0;
        if (t == 255) basearr[NB] = N_EDGES;
    }
    __syncthreads();
    int base0 = b * (EPB / 4);
    #pragma unroll
    for (int i = 0; i < EPB / 1024; i++) {
        int4 sv = src4[base0 + i * 256 + t];
        int4 dv = dst4[base0 + i * 256 + t];
        unsigned p;
        p = atomicAdd(&cur[dv.x >> 9], 1u);
        elist[p] = ((unsigned)sv.x << 9) | (unsigned)(dv.x & 511);
        p = atomicAdd(&cur[dv.y >> 9], 1u);
        elist[p] = ((unsigned)sv.y << 9) | (unsigned)(dv.y & 511);
        p = atomicAdd(&cur[dv.z >> 9], 1u);
        elist[p] = ((unsigned)sv.z << 9) | (unsigned)(dv.z & 511);
        p = atomicAdd(&cur[dv.w >> 9], 1u);
        elist[p] = ((unsigned)sv.w << 9) | (unsigned)(dv.w & 511);
    }
}

// ==== K4: per-bucket degree count -> inv_sqrt, y = x*inv ====
__global__ void k4_b1(const unsigned* __restrict__ basearr, const unsigned* __restrict__ elist,
                      const float* __restrict__ x, float* __restrict__ inv, float* __restrict__ y) {
    __shared__ unsigned cnt[BN];
    int t = threadIdx.x, b = blockIdx.x;
    cnt[t] = 0u; cnt[t + 256] = 0u;
    __syncthreads();
    unsigned lo = basearr[b], hi = basearr[b + 1];
    for (unsigned j = lo + t; j < hi; j += 256)
        atomicAdd(&cnt[elist[j] & 511u], 1u);
    __syncthreads();
    int i0 = b * BN;
    {
        float iv = rsqrtf((float)(cnt[t] + 1u));         // +1 self-loop
        inv[i0 + t] = iv;
        y[i0 + t] = x[i0 + t] * iv;
    }
    {
        float iv = rsqrtf((float)(cnt[t + 256] + 1u));
        inv[i0 + t + 256] = iv;
        y[i0 + t + 256] = x[i0 + t + 256] * iv;
    }
}

// ==== K5: per-bucket LDS accumulate + fused interp/sigmoid ====
__global__ void k5_b2(const unsigned* __restrict__ basearr, const unsigned* __restrict__ elist,
                      const float* __restrict__ inv, const float* __restrict__ y,
                      const float* __restrict__ T, float* __restrict__ out) {
    __shared__ float accf[BN];
    int t = threadIdx.x, b = blockIdx.x;
    accf[t] = 0.f; accf[t + 256] = 0.f;
    __syncthreads();
    unsigned lo = basearr[b], hi = basearr[b + 1];
    for (unsigned j = lo + t; j < hi; j += 256) {
        unsigned p = elist[j];
        atomicAdd(&accf[p & 511u], y[p >> 9]);
    }
    __syncthreads();
    float inv_step = (float)(G_TAB - 1) / (RHI - RLO);
    int i0 = b * BN;
    #pragma unroll
    for (int k = 0; k < 2; k++) {
        int il = t + k * 256;
        int i = i0 + il;
        float g = inv[i] * (accf[il] + y[i]);
        float u = (g - RLO) * inv_step;
        int j = min(max((int)u, 0), G_TAB - 2);
        float fr = u - (float)j;
        float logit = fmaf(fr, T[j + 1] - T[j], T[j]);
        out[i] = 1.f / (1.f + expf(-logit));
    }
}

extern "C" void kernel_launch(void* const* d_in, const int* in_sizes, int n_in,
                              void* d_out, int out_size, void* d_ws, size_t ws_size,
                              hipStream_t stream) {
    const float* x = (const float*)d_in[0];
    const int* e = (const int*)d_in[1];          // int32 edge_index [2][E]
    const int* src = e;
    const int* dst = e + N_EDGES;
    const float* W0 = (const float*)d_in[2];  const float* B0 = (const float*)d_in[3];
    const float* W1 = (const float*)d_in[4];  const float* B1 = (const float*)d_in[5];
    const float* W2 = (const float*)d_in[6];  const float* B2 = (const float*)d_in[7];
    const float* W3 = (const float*)d_in[8];  const float* B3 = (const float*)d_in[9];
    const float* W4 = (const float*)d_in[10]; const float* B4 = (const float*)d_in[11];
    const float* W5 = (const float*)d_in[12]; const float* B5 = (const float*)d_in[13];
    const float* W6 = (const float*)d_in[14]; const float* B6 = (const float*)d_in[15];
    const float* W7 = (const float*)d_in[16]; const float* B7 = (const float*)d_in[17];
    float* out = (float*)d_out;

    // ws layout (4B words):
    // elist(E) | bh(NB*NAH) | offs(NB*NAH) | totals(NB) | basearr(NB+2) | inv(N) | y(N) | T(G_TAB)
    unsigned* wsu = (unsigned*)d_ws;
    unsigned* elist   = wsu;
    unsigned* bh      = elist + N_EDGES;
    unsigned* offs    = bh + NB * NAH;
    unsigned* totals  = offs + NB * NAH;
    unsigned* basearr = totals + NB;
    float* inv = (float*)(basearr + NB + 2);
    float* y   = inv + N_NODES;
    float* T   = y + N_NODES;

    k1_hist_table<<<NAH + TB, 256, 0, stream>>>(
        (const int4*)dst, bh,
        W0, B0, W1, B1, W2, B2, W3, B3, W4, B4, W5, B5, W6, B6, W7, B7, T);
    k2_s1   <<<NB / 4, 256, 0, stream>>>(bh, offs, totals);
    k3_place<<<NAH, 256, 0, stream>>>((const int4*)src, (const int4*)dst,
                                      offs, totals, basearr, elist);
    k4_b1   <<<NB, 256, 0, stream>>>(basearr, elist, x, inv, y);
    k5_b2   <<<NB, 256, 0, stream>>>(basearr, elist, inv, y, T, out);
}

// Round 8
// 153.319 us; speedup vs baseline: 4.0444x; 1.6100x over previous
//
#include <hip/hip_runtime.h>
#include <math.h>

#define N_NODES 262144
#define N_EDGES 2097152
#define NB 512                  // dst buckets (dst >> 9), 512 nodes each
#define BN 512                  // nodes per bucket
#define NAH 256                 // hist/place slice blocks
#define EPB (N_EDGES / NAH)     // 8192 edges per slice
#define HID 200
#define G_TAB 128
#define RLO (-8.0f)
#define RHI (8.0f)

// ==== K1: histogram (blocks 0..NAH-1) || table (blocks NAH..NAH+G_TAB-1) ====
// 1024 threads. Table: one grid point per block, K split across 4 thread-groups
// so each thread has only 50 independent loads per layer; 16 waves (4/SIMD)
// hide the L2 latency that stalled rounds 5-7.
__global__ __launch_bounds__(1024, 4)
void k1_hist_table(const int4* __restrict__ dst4, unsigned* __restrict__ bh,
                   const float* __restrict__ W0, const float* __restrict__ B0,
                   const float* __restrict__ W1, const float* __restrict__ B1,
                   const float* __restrict__ W2, const float* __restrict__ B2,
                   const float* __restrict__ W3, const float* __restrict__ B3,
                   const float* __restrict__ W4, const float* __restrict__ B4,
                   const float* __restrict__ W5, const float* __restrict__ B5,
                   const float* __restrict__ W6, const float* __restrict__ B6,
                   const float* __restrict__ W7, const float* __restrict__ B7,
                   float* __restrict__ T) {
    __shared__ float smf[2 * 256 + 4 * 256 + 8];   // hs[2][256] | ps[4][256] | scratch
    unsigned* smu = (unsigned*)smf;
    const int tid = threadIdx.x;
    const int b = blockIdx.x;

    if (b < NAH) {
        // ---- histogram of dst into 512 buckets ----
        if (tid < NB) smu[tid] = 0u;
        __syncthreads();
        int base0 = b * (EPB / 4);
        #pragma unroll
        for (int i = 0; i < EPB / 4096; i++) {       // 2 iters @ 1024 threads
            int4 d = dst4[base0 + i * 1024 + tid];
            atomicAdd(&smu[d.x >> 9], 1u);
            atomicAdd(&smu[d.y >> 9], 1u);
            atomicAdd(&smu[d.z >> 9], 1u);
            atomicAdd(&smu[d.w >> 9], 1u);
        }
        __syncthreads();
        if (tid < NB) bh[tid * NAH + b] = smu[tid];  // bucket-major for K2
    } else {
        // ---- table point p: 4-way K-split GEMV per layer ----
        const int p = b - NAH;
        const int g = tid >> 8;          // K-group 0..3
        const int n = tid & 255;         // output neuron (active n<200)
        float* hs = smf;                 // [2][256]
        float* ps = smf + 512;           // [4][256]
        float step = (RHI - RLO) / (float)(G_TAB - 1);
        float gp = RLO + (float)p * step;

        if (g == 0 && n < HID) hs[n] = fmaxf(fmaf(gp, W0[n], B0[n]), 0.f);
        __syncthreads();

        const float* Ws[6] = {W1, W2, W3, W4, W5, W6};
        const float* Bs[6] = {B1, B2, B3, B4, B5, B6};
        int cur = 0;
        for (int l = 0; l < 6; l++) {
            float part = 0.f;
            if (n < HID) {
                const float* Wp = Ws[l] + (g * 50) * HID + n;
                const float* hp = hs + cur * 256 + g * 50;
                #pragma unroll
                for (int k = 0; k < 50; k++)
                    part = fmaf(hp[k], Wp[k * HID], part);
            }
            ps[g * 256 + n] = part;
            __syncthreads();
            if (g == 0 && n < HID) {
                float acc = ps[n] + ps[256 + n] + ps[512 + n] + ps[768 + n] + Bs[l][n];
                hs[(1 - cur) * 256 + n] = fmaxf(acc, 0.f);
            }
            __syncthreads();
            cur = 1 - cur;
        }

        // layer 7: 200 -> 1 dot product (groups 0 only; 4 waves)
        if (g == 0) {
            float part = (n < HID) ? hs[cur * 256 + n] * W7[n] : 0.f;
            #pragma unroll
            for (int o = 32; o > 0; o >>= 1) part += __shfl_down(part, o);
            float* w4 = smf + 512 + 1024;                 // scratch[4]
            if ((n & 63) == 0) w4[n >> 6] = part;
        }
        __syncthreads();
        if (tid == 0) T[p] = smf[512 + 1024] + smf[512 + 1025] +
                             smf[512 + 1026] + smf[512 + 1027] + B7[0];
    }
}

// ==== K2: one wave per bucket — exclusive scan over the NAH slices ====
__global__ void k2_s1(const unsigned* __restrict__ bh, unsigned* __restrict__ offs,
                      unsigned* __restrict__ totals) {
    int lane = threadIdx.x & 63;
    int bk = blockIdx.x * 4 + (threadIdx.x >> 6);    // 4 waves/block
    const uint4* row = (const uint4*)&bh[bk * NAH];  // 64 uint4 = 256 slices
    uint4 v = row[lane];
    unsigned s = v.x + v.y + v.z + v.w;
    unsigned inc = s;
    #pragma unroll
    for (int o = 1; o < 64; o <<= 1) {
        unsigned u = __shfl_up(inc, o);
        if (lane >= o) inc += u;
    }
    unsigned run = inc - s;                          // exclusive
    unsigned* orow = &offs[bk * NAH + lane * 4];
    orow[0] = run; run += v.x;
    orow[1] = run; run += v.y;
    orow[2] = run; run += v.z;
    orow[3] = run;
    if (lane == 63) totals[bk] = inc;
}

// ==== K3: in-block scan of bucket totals + place packed edges ====
__global__ void k3_place(const int4* __restrict__ src4, const int4* __restrict__ dst4,
                         const unsigned* __restrict__ offs, const unsigned* __restrict__ totals,
                         unsigned* __restrict__ basearr, unsigned* __restrict__ elist) {
    __shared__ unsigned cur[NB];
    __shared__ unsigned s[256];
    int t = threadIdx.x, b = blockIdx.x;
    unsigned v0 = totals[2 * t], v1 = totals[2 * t + 1];
    s[t] = v0 + v1;
    __syncthreads();
    for (int o = 1; o < 256; o <<= 1) {
        unsigned u = (t >= o) ? s[t - o] : 0u;
        __syncthreads();
        s[t] += u;
        __syncthreads();
    }
    unsigned excl = s[t] - (v0 + v1);
    cur[2 * t]     = excl      + offs[(2 * t) * NAH + b];
    cur[2 * t + 1] = excl + v0 + offs[(2 * t + 1) * NAH + b];
    if (b == 0) {
        basearr[2 * t] = excl;
        basearr[2 * t + 1] = excl + v0;
        if (t == 255) basearr[NB] = N_EDGES;
    }
    __syncthreads();
    int base0 = b * (EPB / 4);
    #pragma unroll
    for (int i = 0; i < EPB / 1024; i++) {
        int4 sv = src4[base0 + i * 256 + t];
        int4 dv = dst4[base0 + i * 256 + t];
        unsigned p;
        p = atomicAdd(&cur[dv.x >> 9], 1u);
        elist[p] = ((unsigned)sv.x << 9) | (unsigned)(dv.x & 511);
        p = atomicAdd(&cur[dv.y >> 9], 1u);
        elist[p] = ((unsigned)sv.y << 9) | (unsigned)(dv.y & 511);
        p = atomicAdd(&cur[dv.z >> 9], 1u);
        elist[p] = ((unsigned)sv.z << 9) | (unsigned)(dv.z & 511);
        p = atomicAdd(&cur[dv.w >> 9], 1u);
        elist[p] = ((unsigned)sv.w << 9) | (unsigned)(dv.w & 511);
    }
}

// ==== K4: per-bucket degree count -> inv_sqrt, y = x*inv ====
__global__ void k4_b1(const unsigned* __restrict__ basearr, const unsigned* __restrict__ elist,
                      const float* __restrict__ x, float* __restrict__ inv, float* __restrict__ y) {
    __shared__ unsigned cnt[BN];
    int t = threadIdx.x, b = blockIdx.x;
    cnt[t] = 0u; cnt[t + 256] = 0u;
    __syncthreads();
    unsigned lo = basearr[b], hi = basearr[b + 1];
    for (unsigned j = lo + t; j < hi; j += 256)
        atomicAdd(&cnt[elist[j] & 511u], 1u);
    __syncthreads();
    int i0 = b * BN;
    {
        float iv = rsqrtf((float)(cnt[t] + 1u));         // +1 self-loop
        inv[i0 + t] = iv;
        y[i0 + t] = x[i0 + t] * iv;
    }
    {
        float iv = rsqrtf((float)(cnt[t + 256] + 1u));
        inv[i0 + t + 256] = iv;
        y[i0 + t + 256] = x[i0 + t + 256] * iv;
    }
}

// ==== K5: per-bucket LDS accumulate + fused interp/sigmoid ====
__global__ void k5_b2(const unsigned* __restrict__ basearr, const unsigned* __restrict__ elist,
                      const float* __restrict__ inv, const float* __restrict__ y,
                      const float* __restrict__ T, float* __restrict__ out) {
    __shared__ float accf[BN];
    int t = threadIdx.x, b = blockIdx.x;
    accf[t] = 0.f; accf[t + 256] = 0.f;
    __syncthreads();
    unsigned lo = basearr[b], hi = basearr[b + 1];
    for (unsigned j = lo + t; j < hi; j += 256) {
        unsigned p = elist[j];
        atomicAdd(&accf[p & 511u], y[p >> 9]);
    }
    __syncthreads();
    float inv_step = (float)(G_TAB - 1) / (RHI - RLO);
    int i0 = b * BN;
    #pragma unroll
    for (int k = 0; k < 2; k++) {
        int il = t + k * 256;
        int i = i0 + il;
        float g = inv[i] * (accf[il] + y[i]);
        float u = (g - RLO) * inv_step;
        int j = min(max((int)u, 0), G_TAB - 2);
        float fr = u - (float)j;
        float logit = fmaf(fr, T[j + 1] - T[j], T[j]);
        out[i] = 1.f / (1.f + expf(-logit));
    }
}

extern "C" void kernel_launch(void* const* d_in, const int* in_sizes, int n_in,
                              void* d_out, int out_size, void* d_ws, size_t ws_size,
                              hipStream_t stream) {
    const float* x = (const float*)d_in[0];
    const int* e = (const int*)d_in[1];          // int32 edge_index [2][E]
    const int* src = e;
    const int* dst = e + N_EDGES;
    const float* W0 = (const float*)d_in[2];  const float* B0 = (const float*)d_in[3];
    const float* W1 = (const float*)d_in[4];  const float* B1 = (const float*)d_in[5];
    const float* W2 = (const float*)d_in[6];  const float* B2 = (const float*)d_in[7];
    const float* W3 = (const float*)d_in[8];  const float* B3 = (const float*)d_in[9];
    const float* W4 = (const float*)d_in[10]; const float* B4 = (const float*)d_in[11];
    const float* W5 = (const float*)d_in[12]; const float* B5 = (const float*)d_in[13];
    const float* W6 = (const float*)d_in[14]; const float* B6 = (const float*)d_in[15];
    const float* W7 = (const float*)d_in[16]; const float* B7 = (const float*)d_in[17];
    float* out = (float*)d_out;

    // ws layout (4B words):
    // elist(E) | bh(NB*NAH) | offs(NB*NAH) | totals(NB) | basearr(NB+2) | inv(N) | y(N) | T(G_TAB)
    unsigned* wsu = (unsigned*)d_ws;
    unsigned* elist   = wsu;
    unsigned* bh      = elist + N_EDGES;
    unsigned* offs    = bh + NB * NAH;
    unsigned* totals  = offs + NB * NAH;
    unsigned* basearr = totals + NB;
    float* inv = (float*)(basearr + NB + 2);
    float* y   = inv + N_NODES;
    float* T   = y + N_NODES;

    k1_hist_table<<<NAH + G_TAB, 1024, 0, stream>>>(
        (const int4*)dst, bh,
        W0, B0, W1, B1, W2, B2, W3, B3, W4, B4, W5, B5, W6, B6, W7, B7, T);
    k2_s1   <<<NB / 4, 256, 0, stream>>>(bh, offs, totals);
    k3_place<<<NAH, 256, 0, stream>>>((const int4*)src, (const int4*)dst,
                                      offs, totals, basearr, elist);
    k4_b1   <<<NB, 256, 0, stream>>>(basearr, elist, x, inv, y);
    k5_b2   <<<NB, 256, 0, stream>>>(basearr, elist, inv, y, T, out);
}

// Round 9
// 147.796 us; speedup vs baseline: 4.1956x; 1.0374x over previous
//
#include <hip/hip_runtime.h>
#include <math.h>

#define N_NODES 262144
#define N_EDGES 2097152
#define NB 512                  // dst buckets (dst >> 9), 512 nodes each
#define CAP 5120                // per-bucket elist capacity (4096 + 16 sigma)
#define NAH 256                 // hist/place slice blocks
#define EPB (N_EDGES / NAH)     // 8192 edges per slice
#define HID 200
#define G_TAB 128
#define RLO (-8.0f)
#define RHI (8.0f)

// ==== K_A: blocks 0..NAH-1: hist + chunk-reserve + place.
//          blocks NAH..NAH+G_TAB-1: MLP table (K-split GEMV). ====
__global__ __launch_bounds__(1024, 4)
void kA(const int4* __restrict__ src4, const int4* __restrict__ dst4,
        unsigned* __restrict__ gcur, unsigned* __restrict__ elist,
        const float* __restrict__ W0, const float* __restrict__ B0,
        const float* __restrict__ W1, const float* __restrict__ B1,
        const float* __restrict__ W2, const float* __restrict__ B2,
        const float* __restrict__ W3, const float* __restrict__ B3,
        const float* __restrict__ W4, const float* __restrict__ B4,
        const float* __restrict__ W5, const float* __restrict__ B5,
        const float* __restrict__ W6, const float* __restrict__ B6,
        const float* __restrict__ W7, const float* __restrict__ B7,
        float* __restrict__ T) {
    __shared__ float smf[2 * 256 + 4 * 256 + 8];   // table: hs[2][256]|ps[4][256]|scr
    unsigned* smu = (unsigned*)smf;                 // hist: h[512] | cur[512]
    const int tid = threadIdx.x;
    const int b = blockIdx.x;

    if (b < NAH) {
        unsigned* h = smu;          // [512]
        unsigned* cur = smu + 512;  // [512]
        if (tid < NB) h[tid] = 0u;
        __syncthreads();
        int base0 = b * (EPB / 4);
        #pragma unroll
        for (int i = 0; i < EPB / 4096; i++) {       // 2 iters @ 1024 threads
            int4 d = dst4[base0 + i * 1024 + tid];
            atomicAdd(&h[d.x >> 9], 1u);
            atomicAdd(&h[d.y >> 9], 1u);
            atomicAdd(&h[d.z >> 9], 1u);
            atomicAdd(&h[d.w >> 9], 1u);
        }
        __syncthreads();
        if (tid < NB)                                 // reserve chunk in bucket
            cur[tid] = tid * CAP + atomicAdd(&gcur[tid], h[tid]);
        __syncthreads();
        #pragma unroll
        for (int i = 0; i < EPB / 4096; i++) {
            int4 sv = src4[base0 + i * 1024 + tid];
            int4 dv = dst4[base0 + i * 1024 + tid];
            unsigned p;
            p = atomicAdd(&cur[dv.x >> 9], 1u);
            elist[p] = ((unsigned)sv.x << 9) | (unsigned)(dv.x & 511);
            p = atomicAdd(&cur[dv.y >> 9], 1u);
            elist[p] = ((unsigned)sv.y << 9) | (unsigned)(dv.y & 511);
            p = atomicAdd(&cur[dv.z >> 9], 1u);
            elist[p] = ((unsigned)sv.z << 9) | (unsigned)(dv.z & 511);
            p = atomicAdd(&cur[dv.w >> 9], 1u);
            elist[p] = ((unsigned)sv.w << 9) | (unsigned)(dv.w & 511);
        }
    } else {
        // ---- table point p: 4-way K-split GEMV per layer ----
        const int p = b - NAH;
        const int g = tid >> 8;          // K-group 0..3
        const int n = tid & 255;         // output neuron (active n<200)
        float* hs = smf;                 // [2][256]
        float* ps = smf + 512;           // [4][256]
        float step = (RHI - RLO) / (float)(G_TAB - 1);
        float gp = RLO + (float)p * step;

        if (g == 0 && n < HID) hs[n] = fmaxf(fmaf(gp, W0[n], B0[n]), 0.f);
        __syncthreads();

        const float* Ws[6] = {W1, W2, W3, W4, W5, W6};
        const float* Bs[6] = {B1, B2, B3, B4, B5, B6};
        int cur = 0;
        for (int l = 0; l < 6; l++) {
            float part = 0.f;
            if (n < HID) {
                const float* Wp = Ws[l] + (g * 50) * HID + n;
                const float* hp = hs + cur * 256 + g * 50;
                #pragma unroll
                for (int k = 0; k < 50; k++)
                    part = fmaf(hp[k], Wp[k * HID], part);
            }
            ps[g * 256 + n] = part;
            __syncthreads();
            if (g == 0 && n < HID) {
                float acc = ps[n] + ps[256 + n] + ps[512 + n] + ps[768 + n] + Bs[l][n];
                hs[(1 - cur) * 256 + n] = fmaxf(acc, 0.f);
            }
            __syncthreads();
            cur = 1 - cur;
        }
        if (g == 0) {
            float part = (n < HID) ? hs[cur * 256 + n] * W7[n] : 0.f;
            #pragma unroll
            for (int o = 32; o > 0; o >>= 1) part += __shfl_down(part, o);
            float* w4 = smf + 512 + 1024;
            if ((n & 63) == 0) w4[n >> 6] = part;
        }
        __syncthreads();
        if (tid == 0) T[p] = smf[512 + 1024] + smf[512 + 1025] +
                             smf[512 + 1026] + smf[512 + 1027] + B7[0];
    }
}

// ==== K_B: per-bucket degree count -> inv_sqrt, y = x*inv (512 thr) ====
__global__ __launch_bounds__(512)
void kB(const unsigned* __restrict__ gcur, const unsigned* __restrict__ elist,
        const float* __restrict__ x, float* __restrict__ inv, float* __restrict__ y) {
    __shared__ unsigned cnt[NB];
    int t = threadIdx.x, b = blockIdx.x;
    cnt[t] = 0u;
    __syncthreads();
    unsigned lo = b * CAP, hi = b * CAP + gcur[b];
    for (unsigned j = lo + t; j < hi; j += 512)
        atomicAdd(&cnt[elist[j] & 511u], 1u);
    __syncthreads();
    int i = b * 512 + t;
    float iv = rsqrtf((float)(cnt[t] + 1u));      // +1 self-loop
    inv[i] = iv;
    y[i] = x[i] * iv;
}

// ==== K_C: per-bucket LDS accumulate + fused interp/sigmoid (512 thr) ====
__global__ __launch_bounds__(512)
void kC(const unsigned* __restrict__ gcur, const unsigned* __restrict__ elist,
        const float* __restrict__ inv, const float* __restrict__ y,
        const float* __restrict__ T, float* __restrict__ out) {
    __shared__ float accf[NB];
    int t = threadIdx.x, b = blockIdx.x;
    accf[t] = 0.f;
    __syncthreads();
    unsigned lo = b * CAP, hi = b * CAP + gcur[b];
    for (unsigned j = lo + t; j < hi; j += 512) {
        unsigned p = elist[j];
        atomicAdd(&accf[p & 511u], y[p >> 9]);
    }
    __syncthreads();
    float inv_step = (float)(G_TAB - 1) / (RHI - RLO);
    int i = b * 512 + t;
    float g = inv[i] * (accf[t] + y[i]);
    float u = (g - RLO) * inv_step;
    int j = min(max((int)u, 0), G_TAB - 2);
    float fr = u - (float)j;
    float logit = fmaf(fr, T[j + 1] - T[j], T[j]);
    out[i] = 1.f / (1.f + expf(-logit));
}

extern "C" void kernel_launch(void* const* d_in, const int* in_sizes, int n_in,
                              void* d_out, int out_size, void* d_ws, size_t ws_size,
                              hipStream_t stream) {
    const float* x = (const float*)d_in[0];
    const int* e = (const int*)d_in[1];          // int32 edge_index [2][E]
    const int* src = e;
    const int* dst = e + N_EDGES;
    const float* W0 = (const float*)d_in[2];  const float* B0 = (const float*)d_in[3];
    const float* W1 = (const float*)d_in[4];  const float* B1 = (const float*)d_in[5];
    const float* W2 = (const float*)d_in[6];  const float* B2 = (const float*)d_in[7];
    const float* W3 = (const float*)d_in[8];  const float* B3 = (const float*)d_in[9];
    const float* W4 = (const float*)d_in[10]; const float* B4 = (const float*)d_in[11];
    const float* W5 = (const float*)d_in[12]; const float* B5 = (const float*)d_in[13];
    const float* W6 = (const float*)d_in[14]; const float* B6 = (const float*)d_in[15];
    const float* W7 = (const float*)d_in[16]; const float* B7 = (const float*)d_in[17];
    float* out = (float*)d_out;

    // ws layout (4B words): elist(NB*CAP) | gcur(NB) | inv(N) | y(N) | T(G_TAB)
    unsigned* wsu = (unsigned*)d_ws;
    unsigned* elist = wsu;
    unsigned* gcur  = elist + NB * CAP;
    float* inv = (float*)(gcur + NB);
    float* y   = inv + N_NODES;
    float* T   = y + N_NODES;

    hipMemsetAsync(gcur, 0, NB * sizeof(unsigned), stream);
    kA<<<NAH + G_TAB, 1024, 0, stream>>>(
        (const int4*)src, (const int4*)dst, gcur, elist,
        W0, B0, W1, B1, W2, B2, W3, B3, W4, B4, W5, B5, W6, B6, W7, B7, T);
    kB<<<NB, 512, 0, stream>>>(gcur, elist, x, inv, y);
    kC<<<NB, 512, 0, stream>>>(gcur, elist, inv, y, T, out);
}

// Round 10
// 146.248 us; speedup vs baseline: 4.2400x; 1.0106x over previous
//
#include <hip/hip_runtime.h>
#include <math.h>

#define N_NODES 262144
#define N_EDGES 2097152
#define NB 512                  // dst buckets (dst >> 9), 512 nodes each
#define NAH 256                 // sort slice blocks
#define EPB (N_EDGES / NAH)     // 8192 edges per slice
#define ROW 513                 // bhoff row length (512 offsets + sentinel)
#define HID 200
#define G_TAB 128
#define RLO (-8.0f)
#define RHI (8.0f)

// ==== K_A: blocks 0..NAH-1: register-load + LDS hist + scan + LDS sort +
//           coalesced write of block-major elist. No global atomics.
//          blocks NAH..NAH+G_TAB-1: MLP table (K-split GEMV). ====
__global__ __launch_bounds__(1024)
void kA(const int4* __restrict__ src4, const int4* __restrict__ dst4,
        unsigned* __restrict__ elist, unsigned* __restrict__ bhoff,
        const float* __restrict__ W0, const float* __restrict__ B0,
        const float* __restrict__ W1, const float* __restrict__ B1,
        const float* __restrict__ W2, const float* __restrict__ B2,
        const float* __restrict__ W3, const float* __restrict__ B3,
        const float* __restrict__ W4, const float* __restrict__ B4,
        const float* __restrict__ W5, const float* __restrict__ B5,
        const float* __restrict__ W6, const float* __restrict__ B6,
        const float* __restrict__ W7, const float* __restrict__ B7,
        float* __restrict__ T) {
    __shared__ unsigned smu[512 + 512 + EPB];     // h | cur | sorted = 36 KB
    const int tid = threadIdx.x;
    const int b = blockIdx.x;

    if (b < NAH) {
        unsigned* h = smu;
        unsigned* cur = smu + 512;
        unsigned* sorted = smu + 1024;
        if (tid < 512) h[tid] = 0u;
        __syncthreads();
        // load this block's 8192 edges into registers (one global read)
        int base0 = b * (EPB / 4);
        int4 dv[2], sv[2];
        #pragma unroll
        for (int i = 0; i < 2; i++) {
            dv[i] = dst4[base0 + i * 1024 + tid];
            sv[i] = src4[base0 + i * 1024 + tid];
        }
        #pragma unroll
        for (int i = 0; i < 2; i++) {
            atomicAdd(&h[dv[i].x >> 9], 1u);
            atomicAdd(&h[dv[i].y >> 9], 1u);
            atomicAdd(&h[dv[i].z >> 9], 1u);
            atomicAdd(&h[dv[i].w >> 9], 1u);
        }
        __syncthreads();
        unsigned mine = (tid < 512) ? h[tid] : 0u;
        // inclusive scan of h in place (all threads hit barriers)
        for (int o = 1; o < 512; o <<= 1) {
            unsigned v = 0u;
            if (tid < 512 && tid >= o) v = h[tid - o];
            __syncthreads();
            if (tid < 512) h[tid] += v;
            __syncthreads();
        }
        if (tid < 512) {
            unsigned excl = h[tid] - mine;
            cur[tid] = excl;
            bhoff[b * ROW + tid] = excl;
            if (tid == 0) bhoff[b * ROW + 512] = EPB;   // sentinel
        }
        __syncthreads();
        // place into LDS staging, sorted by bucket
        #pragma unroll
        for (int i = 0; i < 2; i++) {
            unsigned p;
            p = atomicAdd(&cur[dv[i].x >> 9], 1u);
            sorted[p] = ((unsigned)sv[i].x << 9) | (unsigned)(dv[i].x & 511);
            p = atomicAdd(&cur[dv[i].y >> 9], 1u);
            sorted[p] = ((unsigned)sv[i].y << 9) | (unsigned)(dv[i].y & 511);
            p = atomicAdd(&cur[dv[i].z >> 9], 1u);
            sorted[p] = ((unsigned)sv[i].z << 9) | (unsigned)(dv[i].z & 511);
            p = atomicAdd(&cur[dv[i].w >> 9], 1u);
            sorted[p] = ((unsigned)sv[i].w << 9) | (unsigned)(dv[i].w & 511);
        }
        __syncthreads();
        // coalesced copy-out: 32 KB contiguous per block
        uint4* el4 = (uint4*)(elist + b * EPB);
        const uint4* so4 = (const uint4*)sorted;
        #pragma unroll
        for (int i = 0; i < 2; i++)
            el4[i * 1024 + tid] = so4[i * 1024 + tid];
    } else {
        // ---- table point p: 4-way K-split GEMV per layer ----
        float* smf = (float*)smu;        // hs[2][256] | ps[4][256] | scr[8]
        const int p = b - NAH;
        const int g = tid >> 8;          // K-group 0..3
        const int n = tid & 255;         // output neuron (active n<200)
        float* hs = smf;
        float* ps = smf + 512;
        float step = (RHI - RLO) / (float)(G_TAB - 1);
        float gp = RLO + (float)p * step;

        if (g == 0 && n < HID) hs[n] = fmaxf(fmaf(gp, W0[n], B0[n]), 0.f);
        __syncthreads();

        const float* Ws[6] = {W1, W2, W3, W4, W5, W6};
        const float* Bs[6] = {B1, B2, B3, B4, B5, B6};
        int cur = 0;
        for (int l = 0; l < 6; l++) {
            float part = 0.f;
            if (n < HID) {
                const float* Wp = Ws[l] + (g * 50) * HID + n;
                const float* hp = hs + cur * 256 + g * 50;
                #pragma unroll
                for (int k = 0; k < 50; k++)
                    part = fmaf(hp[k], Wp[k * HID], part);
            }
            ps[g * 256 + n] = part;
            __syncthreads();
            if (g == 0 && n < HID) {
                float acc = ps[n] + ps[256 + n] + ps[512 + n] + ps[768 + n] + Bs[l][n];
                hs[(1 - cur) * 256 + n] = fmaxf(acc, 0.f);
            }
            __syncthreads();
            cur = 1 - cur;
        }
        if (g == 0) {
            float part = (n < HID) ? hs[cur * 256 + n] * W7[n] : 0.f;
            #pragma unroll
            for (int o = 32; o > 0; o >>= 1) part += __shfl_down(part, o);
            float* w4 = smf + 512 + 1024;
            if ((n & 63) == 0) w4[n >> 6] = part;
        }
        __syncthreads();
        if (tid == 0) T[p] = smf[512 + 1024] + smf[512 + 1025] +
                             smf[512 + 1026] + smf[512 + 1027] + B7[0];
    }
}

// ==== K_B: bucket k: count degree from 256 fragments -> inv_sqrt, y ====
__global__ __launch_bounds__(512)
void kB(const unsigned* __restrict__ bhoff, const unsigned* __restrict__ elist,
        const float* __restrict__ x, float* __restrict__ inv, float* __restrict__ y) {
    __shared__ unsigned cnt[512];
    int t = threadIdx.x, k = blockIdx.x;
    cnt[t] = 0u;
    __syncthreads();
    int f = t >> 1, half = t & 1;                  // 2 threads per fragment
    unsigned off = bhoff[f * ROW + k];
    unsigned end = bhoff[f * ROW + k + 1];
    const unsigned* ep = elist + f * EPB;
    for (unsigned j = off + half; j < end; j += 2)
        atomicAdd(&cnt[ep[j] & 511u], 1u);
    __syncthreads();
    int i = k * 512 + t;
    float iv = rsqrtf((float)(cnt[t] + 1u));       // +1 self-loop
    inv[i] = iv;
    y[i] = x[i] * iv;
}

// ==== K_C: bucket k: accumulate y[src] + fused interp/sigmoid ====
__global__ __launch_bounds__(512)
void kC(const unsigned* __restrict__ bhoff, const unsigned* __restrict__ elist,
        const float* __restrict__ inv, const float* __restrict__ y,
        const float* __restrict__ T, float* __restrict__ out) {
    __shared__ float accf[512];
    int t = threadIdx.x, k = blockIdx.x;
    accf[t] = 0.f;
    __syncthreads();
    int f = t >> 1, half = t & 1;
    unsigned off = bhoff[f * ROW + k];
    unsigned end = bhoff[f * ROW + k + 1];
    const unsigned* ep = elist + f * EPB;
    for (unsigned j = off + half; j < end; j += 2) {
        unsigned p = ep[j];
        atomicAdd(&accf[p & 511u], y[p >> 9]);
    }
    __syncthreads();
    float inv_step = (float)(G_TAB - 1) / (RHI - RLO);
    int i = k * 512 + t;
    float g = inv[i] * (accf[t] + y[i]);
    float u = (g - RLO) * inv_step;
    int j = min(max((int)u, 0), G_TAB - 2);
    float fr = u - (float)j;
    float logit = fmaf(fr, T[j + 1] - T[j], T[j]);
    out[i] = 1.f / (1.f + expf(-logit));
}

extern "C" void kernel_launch(void* const* d_in, const int* in_sizes, int n_in,
                              void* d_out, int out_size, void* d_ws, size_t ws_size,
                              hipStream_t stream) {
    const float* x = (const float*)d_in[0];
    const int* e = (const int*)d_in[1];          // int32 edge_index [2][E]
    const int* src = e;
    const int* dst = e + N_EDGES;
    const float* W0 = (const float*)d_in[2];  const float* B0 = (const float*)d_in[3];
    const float* W1 = (const float*)d_in[4];  const float* B1 = (const float*)d_in[5];
    const float* W2 = (const float*)d_in[6];  const float* B2 = (const float*)d_in[7];
    const float* W3 = (const float*)d_in[8];  const float* B3 = (const float*)d_in[9];
    const float* W4 = (const float*)d_in[10]; const float* B4 = (const float*)d_in[11];
    const float* W5 = (const float*)d_in[12]; const float* B5 = (const float*)d_in[13];
    const float* W6 = (const float*)d_in[14]; const float* B6 = (const float*)d_in[15];
    const float* W7 = (const float*)d_in[16]; const float* B7 = (const float*)d_in[17];
    float* out = (float*)d_out;

    // ws layout (4B words): elist(E) | bhoff(NAH*ROW) | inv(N) | y(N) | T(G_TAB)
    unsigned* wsu = (unsigned*)d_ws;
    unsigned* elist = wsu;
    unsigned* bhoff = elist + N_EDGES;
    float* inv = (float*)(bhoff + NAH * ROW);
    float* y   = inv + N_NODES;
    float* T   = y + N_NODES;

    kA<<<NAH + G_TAB, 1024, 0, stream>>>(
        (const int4*)src, (const int4*)dst, elist, bhoff,
        W0, B0, W1, B1, W2, B2, W3, B3, W4, B4, W5, B5, W6, B6, W7, B7, T);
    kB<<<NB, 512, 0, stream>>>(bhoff, elist, x, inv, y);
    kC<<<NB, 512, 0, stream>>>(bhoff, elist, inv, y, T, out);
}

// Round 11
// 143.292 us; speedup vs baseline: 4.3274x; 1.0206x over previous
//
#include <hip/hip_runtime.h>
#include <math.h>

#define N_NODES 262144
#define N_EDGES 2097152
#define NB 512                  // dst buckets (dst >> 9), 512 nodes each
#define NAH 256                 // sort slice blocks
#define EPB (N_EDGES / NAH)     // 8192 edges per slice
#define ROW 513                 // bhoff row length (512 offsets + sentinel)
#define HID 200
#define G_TAB 128
#define RLO (-8.0f)
#define RHI (8.0f)

// ==== K_A: blocks 0..NAH-1: register-load + LDS hist + wave-scan + LDS sort +
//           coalesced write of block-major elist. No global atomics.
//          blocks NAH..NAH+G_TAB-1: MLP table (K-split GEMV). ====
__global__ __launch_bounds__(1024)
void kA(const int4* __restrict__ src4, const int4* __restrict__ dst4,
        unsigned* __restrict__ elist, unsigned* __restrict__ bhoff,
        const float* __restrict__ W0, const float* __restrict__ B0,
        const float* __restrict__ W1, const float* __restrict__ B1,
        const float* __restrict__ W2, const float* __restrict__ B2,
        const float* __restrict__ W3, const float* __restrict__ B3,
        const float* __restrict__ W4, const float* __restrict__ B4,
        const float* __restrict__ W5, const float* __restrict__ B5,
        const float* __restrict__ W6, const float* __restrict__ B6,
        const float* __restrict__ W7, const float* __restrict__ B7,
        float* __restrict__ T) {
    __shared__ unsigned smu[512 + 512 + EPB];     // h | cur | sorted = 36 KB
    const int tid = threadIdx.x;
    const int b = blockIdx.x;

    if (b < NAH) {
        unsigned* h = smu;
        unsigned* cur = smu + 512;
        unsigned* sorted = smu + 1024;
        if (tid < 512) h[tid] = 0u;
        __syncthreads();
        // load this block's 8192 edges into registers (one global read)
        int base0 = b * (EPB / 4);
        int4 dv[2], sv[2];
        #pragma unroll
        for (int i = 0; i < 2; i++) {
            dv[i] = dst4[base0 + i * 1024 + tid];
            sv[i] = src4[base0 + i * 1024 + tid];
        }
        #pragma unroll
        for (int i = 0; i < 2; i++) {
            atomicAdd(&h[dv[i].x >> 9], 1u);
            atomicAdd(&h[dv[i].y >> 9], 1u);
            atomicAdd(&h[dv[i].z >> 9], 1u);
            atomicAdd(&h[dv[i].w >> 9], 1u);
        }
        __syncthreads();
        // single-wave exclusive scan: lane owns 8 consecutive bins
        if (tid < 64) {
            unsigned v[8];
            unsigned run = 0;
            #pragma unroll
            for (int i = 0; i < 8; i++) {
                unsigned c = h[tid * 8 + i];
                v[i] = run;            // exclusive within chunk
                run += c;
            }
            unsigned inc = run;
            #pragma unroll
            for (int o = 1; o < 64; o <<= 1) {
                unsigned u = __shfl_up(inc, o);
                if (tid >= o) inc += u;
            }
            unsigned cbase = inc - run;
            unsigned* bh = &bhoff[b * ROW];
            #pragma unroll
            for (int i = 0; i < 8; i++) {
                unsigned excl = cbase + v[i];
                cur[tid * 8 + i] = excl;
                bh[tid * 8 + i] = excl;
            }
            if (tid == 0) bh[512] = EPB;   // sentinel
        }
        __syncthreads();
        // place into LDS staging, sorted by bucket
        #pragma unroll
        for (int i = 0; i < 2; i++) {
            unsigned p;
            p = atomicAdd(&cur[dv[i].x >> 9], 1u);
            sorted[p] = ((unsigned)sv[i].x << 9) | (unsigned)(dv[i].x & 511);
            p = atomicAdd(&cur[dv[i].y >> 9], 1u);
            sorted[p] = ((unsigned)sv[i].y << 9) | (unsigned)(dv[i].y & 511);
            p = atomicAdd(&cur[dv[i].z >> 9], 1u);
            sorted[p] = ((unsigned)sv[i].z << 9) | (unsigned)(dv[i].z & 511);
            p = atomicAdd(&cur[dv[i].w >> 9], 1u);
            sorted[p] = ((unsigned)sv[i].w << 9) | (unsigned)(dv[i].w & 511);
        }
        __syncthreads();
        // coalesced copy-out: 32 KB contiguous per block
        uint4* el4 = (uint4*)(elist + b * EPB);
        const uint4* so4 = (const uint4*)sorted;
        #pragma unroll
        for (int i = 0; i < 2; i++)
            el4[i * 1024 + tid] = so4[i * 1024 + tid];
    } else {
        // ---- table point p: 4-way K-split GEMV per layer ----
        float* smf = (float*)smu;        // hs[2][256] | ps[4][256] | scr[8]
        const int p = b - NAH;
        const int g = tid >> 8;          // K-group 0..3
        const int n = tid & 255;         // output neuron (active n<200)
        float* hs = smf;
        float* ps = smf + 512;
        float step = (RHI - RLO) / (float)(G_TAB - 1);
        float gp = RLO + (float)p * step;

        if (g == 0 && n < HID) hs[n] = fmaxf(fmaf(gp, W0[n], B0[n]), 0.f);
        __syncthreads();

        const float* Ws[6] = {W1, W2, W3, W4, W5, W6};
        const float* Bs[6] = {B1, B2, B3, B4, B5, B6};
        int cur = 0;
        for (int l = 0; l < 6; l++) {
            float part = 0.f;
            if (n < HID) {
                const float* Wp = Ws[l] + (g * 50) * HID + n;
                const float* hp = hs + cur * 256 + g * 50;
                #pragma unroll
                for (int k = 0; k < 50; k++)
                    part = fmaf(hp[k], Wp[k * HID], part);
            }
            ps[g * 256 + n] = part;
            __syncthreads();
            if (g == 0 && n < HID) {
                float acc = ps[n] + ps[256 + n] + ps[512 + n] + ps[768 + n] + Bs[l][n];
                hs[(1 - cur) * 256 + n] = fmaxf(acc, 0.f);
            }
            __syncthreads();
            cur = 1 - cur;
        }
        if (g == 0) {
            float part = (n < HID) ? hs[cur * 256 + n] * W7[n] : 0.f;
            #pragma unroll
            for (int o = 32; o > 0; o >>= 1) part += __shfl_down(part, o);
            float* w4 = smf + 512 + 1024;
            if ((n & 63) == 0) w4[n >> 6] = part;
        }
        __syncthreads();
        if (tid == 0) T[p] = smf[512 + 1024] + smf[512 + 1025] +
                             smf[512 + 1026] + smf[512 + 1027] + B7[0];
    }
}

// ==== K_B: bucket k: count degree from 256 fragments -> y = x * rsqrt(deg+1) ====
__global__ __launch_bounds__(512)
void kB(const unsigned* __restrict__ bhoff, const unsigned* __restrict__ elist,
        const float* __restrict__ x, float* __restrict__ y) {
    __shared__ unsigned cnt[512];
    int t = threadIdx.x, k = blockIdx.x;
    cnt[t] = 0u;
    __syncthreads();
    int f = t >> 1, half = t & 1;                  // 2 threads per fragment
    unsigned off = bhoff[f * ROW + k];
    unsigned end = bhoff[f * ROW + k + 1];
    const unsigned* ep = elist + f * EPB;
    for (unsigned j = off + half; j < end; j += 2)
        atomicAdd(&cnt[ep[j] & 511u], 1u);
    __syncthreads();
    int i = k * 512 + t;
    y[i] = x[i] * rsqrtf((float)(cnt[t] + 1u));    // +1 self-loop
}

// ==== K_C: bucket k: cnt + accumulate y[src] in one pass -> interp/sigmoid ====
__global__ __launch_bounds__(512)
void kC(const unsigned* __restrict__ bhoff, const unsigned* __restrict__ elist,
        const float* __restrict__ x, const float* __restrict__ y,
        const float* __restrict__ T, float* __restrict__ out) {
    __shared__ float accf[512];
    __shared__ unsigned cnt[512];
    int t = threadIdx.x, k = blockIdx.x;
    accf[t] = 0.f;
    cnt[t] = 0u;
    __syncthreads();
    int f = t >> 1, half = t & 1;
    unsigned off = bhoff[f * ROW + k];
    unsigned end = bhoff[f * ROW + k + 1];
    const unsigned* ep = elist + f * EPB;
    for (unsigned j = off + half; j < end; j += 2) {
        unsigned p = ep[j];
        unsigned dl = p & 511u;
        atomicAdd(&cnt[dl], 1u);
        atomicAdd(&accf[dl], y[p >> 9]);
    }
    __syncthreads();
    float inv_step = (float)(G_TAB - 1) / (RHI - RLO);
    int i = k * 512 + t;
    float iv = rsqrtf((float)(cnt[t] + 1u));       // +1 self-loop
    float g = iv * (accf[t] + x[i] * iv);          // y_self = x*iv
    float u = (g - RLO) * inv_step;
    int j = min(max((int)u, 0), G_TAB - 2);
    float fr = u - (float)j;
    float logit = fmaf(fr, T[j + 1] - T[j], T[j]);
    out[i] = 1.f / (1.f + expf(-logit));
}

extern "C" void kernel_launch(void* const* d_in, const int* in_sizes, int n_in,
                              void* d_out, int out_size, void* d_ws, size_t ws_size,
                              hipStream_t stream) {
    const float* x = (const float*)d_in[0];
    const int* e = (const int*)d_in[1];          // int32 edge_index [2][E]
    const int* src = e;
    const int* dst = e + N_EDGES;
    const float* W0 = (const float*)d_in[2];  const float* B0 = (const float*)d_in[3];
    const float* W1 = (const float*)d_in[4];  const float* B1 = (const float*)d_in[5];
    const float* W2 = (const float*)d_in[6];  const float* B2 = (const float*)d_in[7];
    const float* W3 = (const float*)d_in[8];  const float* B3 = (const float*)d_in[9];
    const float* W4 = (const float*)d_in[10]; const float* B4 = (const float*)d_in[11];
    const float* W5 = (const float*)d_in[12]; const float* B5 = (const float*)d_in[13];
    const float* W6 = (const float*)d_in[14]; const float* B6 = (const float*)d_in[15];
    const float* W7 = (const float*)d_in[16]; const float* B7 = (const float*)d_in[17];
    float* out = (float*)d_out;

    // ws layout (4B words): elist(E) | bhoff(NAH*ROW) | y(N) | T(G_TAB)
    unsigned* wsu = (unsigned*)d_ws;
    unsigned* elist = wsu;
    unsigned* bhoff = elist + N_EDGES;
    float* y = (float*)(bhoff + NAH * ROW);
    float* T = y + N_NODES;

    kA<<<NAH + G_TAB, 1024, 0, stream>>>(
        (const int4*)src, (const int4*)dst, elist, bhoff,
        W0, B0, W1, B1, W2, B2, W3, B3, W4, B4, W5, B5, W6, B6, W7, B7, T);
    kB<<<NB, 512, 0, stream>>>(bhoff, elist, x, y);
    kC<<<NB, 512, 0, stream>>>(bhoff, elist, x, y, T, out);
}